// Round 6
// baseline (138.553 us; speedup 1.0000x reference)
//
#include <hip/hip_runtime.h>

#define NSEQ 2048
#define DH 64
#define SCALE 0.125f
#define QBLK 256
#define KVBLK 64
#define NTILE (NSEQ / KVBLK)
#define KP 72   // Kt row pitch (144B): conflict-minimal b128 reads + writes

typedef _Float16 f16x8 __attribute__((ext_vector_type(8)));
typedef _Float16 f16x4 __attribute__((ext_vector_type(4)));
typedef __fp16 fp16x2 __attribute__((ext_vector_type(2)));
typedef float f32x4 __attribute__((ext_vector_type(4)));
typedef unsigned u32x2 __attribute__((ext_vector_type(2)));

union TrP { f16x4 h[2]; f16x8 v8; };

// tr-read: per-lane addr = subtile_base + l15*8; HW delivers column l15 of the
// 128B-aligned 4x16 f16 subtile. Subtile bases MUST be 128B-aligned.
#define TRRD(dst, bb, lit) \
    asm volatile("ds_read_b64_tr_b16 %0, %1 offset:" lit : "=v"(dst) : "v"(bb))

__global__ __launch_bounds__(512, 4)
void fa_fwd(const float* __restrict__ Qg, const float* __restrict__ Kg,
            const float* __restrict__ Vg, float* __restrict__ Og)
{
    __shared__ _Float16 Kt[2][KVBLK * KP];   // 18432 B, double-buffered
    __shared__ _Float16 Vt[2][KVBLK * DH];   // 16384 B, subtiled [kv/4][d/16][4][16]

    const int tid  = threadIdx.x;
    const int lane = tid & 63;
    const int wv   = tid >> 6;
    const int l15  = lane & 15;
    const int g    = lane >> 4;

    // XCD-aware swizzle: 512 blocks / 8 XCDs
    const int id  = blockIdx.x;
    const int w   = (id & 7) * 64 + (id >> 3);
    const int bh  = w >> 3;
    const int qb0 = (w & 7) * QBLK;
    const size_t base = (size_t)bh * NSEQ * DH;

    f16x8 qf[2][2];
#pragma unroll
    for (int u = 0; u < 2; ++u) {
        const float* qp = Qg + base + (size_t)(qb0 + wv * 32 + u * 16 + l15) * DH;
#pragma unroll
        for (int ks = 0; ks < 2; ++ks)
#pragma unroll
            for (int j = 0; j < 8; ++j)
                qf[u][ks][j] = (_Float16)(qp[32 * ks + 8 * g + j] * SCALE);
    }

    f32x4 acc[2][4];
#pragma unroll
    for (int u = 0; u < 2; ++u)
#pragma unroll
        for (int nt = 0; nt < 4; ++nt)
            acc[u][nt] = (f32x4){0.f, 0.f, 0.f, 0.f};
    float m_run[2] = {-INFINITY, -INFINITY};
    float l_run[2] = {0.f, 0.f};

    // staging map: each thread 2 float4 per K and V
    const int ea  = tid * 4;
    const int eb  = 2048 + tid * 4;
    const int kva = ea >> 6, d0a = ea & 63;
    const int kvb = eb >> 6, d0b = eb & 63;
    const float* Kbp = Kg + base;
    const float* Vbp = Vg + base;
    const int vta = ((kva >> 2) * 4 + (d0a >> 4)) * 64 + (kva & 3) * 16 + (d0a & 15);
    const int vtb = ((kvb >> 2) * 4 + (d0b >> 4)) * 64 + (kvb & 3) * 16 + (d0b & 15);

    float4 kra, krb, vra, vrb;
    kra = *(const float4*)(Kbp + kva * DH + d0a);
    krb = *(const float4*)(Kbp + kvb * DH + d0b);
    vra = *(const float4*)(Vbp + kva * DH + d0a);
    vrb = *(const float4*)(Vbp + kvb * DH + d0b);

#define STAGE_WRITE(bb) do { \
        f16x4 h; \
        h[0] = (_Float16)kra.x; h[1] = (_Float16)kra.y; h[2] = (_Float16)kra.z; h[3] = (_Float16)kra.w; \
        *(f16x4*)&Kt[bb][kva * KP + d0a] = h; \
        h[0] = (_Float16)krb.x; h[1] = (_Float16)krb.y; h[2] = (_Float16)krb.z; h[3] = (_Float16)krb.w; \
        *(f16x4*)&Kt[bb][kvb * KP + d0b] = h; \
        h[0] = (_Float16)vra.x; h[1] = (_Float16)vra.y; h[2] = (_Float16)vra.z; h[3] = (_Float16)vra.w; \
        *(f16x4*)&Vt[bb][vta] = h; \
        h[0] = (_Float16)vrb.x; h[1] = (_Float16)vrb.y; h[2] = (_Float16)vrb.z; h[3] = (_Float16)vrb.w; \
        *(f16x4*)&Vt[bb][vtb] = h; \
    } while (0)

    STAGE_WRITE(0);
    __syncthreads();

    const unsigned vtrb = (unsigned)(size_t)(&Vt[0][0]) + (unsigned)(g * 1024 + l15 * 8);

    for (int t = 0; t < NTILE; ++t) {
        const int c = t & 1;

        // T14: issue next tile's global loads before compute
        if (t + 1 < NTILE) {
            const float* kp = Kbp + (size_t)(t + 1) * KVBLK * DH;
            const float* vp = Vbp + (size_t)(t + 1) * KVBLK * DH;
            kra = *(const float4*)(kp + kva * DH + d0a);
            krb = *(const float4*)(kp + kvb * DH + d0b);
            vra = *(const float4*)(vp + kva * DH + d0a);
            vrb = *(const float4*)(vp + kvb * DH + d0b);
        }

        f16x8 kf[4][2];
#pragma unroll
        for (int mt = 0; mt < 4; ++mt)
#pragma unroll
            for (int ks = 0; ks < 2; ++ks)
                kf[mt][ks] = *(const f16x8*)&Kt[c][(l15 + 16 * mt) * KP + 32 * ks + 8 * g];

        // tr-read bases: subtile (kv4 = 8ks+2g+h2, d16 = nt) at 128B-aligned offsets
        const unsigned vb  = vtrb + (unsigned)(c * 8192);
        const unsigned b00 = vb;            // ks=0, h2=0
        const unsigned b01 = vb + 512u;     // ks=0, h2=1
        const unsigned b10 = vb + 4096u;    // ks=1, h2=0
        const unsigned b11 = vb + 4608u;    // ks=1, h2=1

#pragma unroll
        for (int u = 0; u < 2; ++u) {
            f32x4 s[4];
            __builtin_amdgcn_s_setprio(1);
#pragma unroll
            for (int mt = 0; mt < 4; ++mt) {
                s[mt] = (f32x4){0.f, 0.f, 0.f, 0.f};
#pragma unroll
                for (int ks = 0; ks < 2; ++ks)
                    s[mt] = __builtin_amdgcn_mfma_f32_16x16x32_f16(kf[mt][ks], qf[u][ks], s[mt], 0, 0, 0);
            }
            __builtin_amdgcn_s_setprio(0);

            float tmax = -INFINITY;
#pragma unroll
            for (int mt = 0; mt < 4; ++mt)
#pragma unroll
                for (int r = 0; r < 4; ++r) tmax = fmaxf(tmax, s[mt][r]);
            tmax = fmaxf(tmax, __shfl_xor(tmax, 16));
            tmax = fmaxf(tmax, __shfl_xor(tmax, 32));

            // T13 defer-max
            if (!__all(tmax <= m_run[u] + 8.f)) {
                const float m_new = fmaxf(m_run[u], tmax);
                const float fac = __expf(m_run[u] - m_new);
                l_run[u] *= fac;
                m_run[u] = m_new;
#pragma unroll
                for (int r = 0; r < 4; ++r) {
                    const float fr = __shfl(fac, 4 * g + r);
#pragma unroll
                    for (int nt = 0; nt < 4; ++nt) acc[u][nt][r] *= fr;
                }
            }

            // P = exp(s - m) packed straight to f16 pairs: W[mt][h] = P pair
            // at kv base 16mt + 4g + 2h (q = l15)
            unsigned W[4][2];
            float psum = 0.f;
#pragma unroll
            for (int mt = 0; mt < 4; ++mt) {
                float p0 = __expf(s[mt][0] - m_run[u]);
                float p1 = __expf(s[mt][1] - m_run[u]);
                float p2 = __expf(s[mt][2] - m_run[u]);
                float p3 = __expf(s[mt][3] - m_run[u]);
                psum += (p0 + p1) + (p2 + p3);
                union { fp16x2 f2; unsigned w; } u0, u1;
                u0.f2 = __builtin_amdgcn_cvt_pkrtz(p0, p1);
                u1.f2 = __builtin_amdgcn_cvt_pkrtz(p2, p3);
                W[mt][0] = u0.w;
                W[mt][1] = u1.w;
            }
            psum += __shfl_xor(psum, 16);
            psum += __shfl_xor(psum, 32);
            l_run[u] += psum;

            // T12: route W words to PV A-fragment layout.
            // a=W[2kk][h], b=W[2kk+1][h]; 32-swap then 16-swap ->
            // T[kk][h], T[kk][2+h] = P pairs at kv base 32kk + 8g + 2j'
            unsigned T[2][4];
#pragma unroll
            for (int kk = 0; kk < 2; ++kk)
#pragma unroll
                for (int h = 0; h < 2; ++h) {
                    u32x2 r1 = __builtin_amdgcn_permlane32_swap(W[2 * kk][h], W[2 * kk + 1][h], false, false);
                    u32x2 r2 = __builtin_amdgcn_permlane16_swap(r1[0], r1[1], false, false);
                    T[kk][h]     = r2[0];
                    T[kk][2 + h] = r2[1];
                }

#pragma unroll
            for (int ks = 0; ks < 2; ++ks) {
                TrP tp[4];
                const unsigned bh0 = ks ? b10 : b00;
                const unsigned bh1 = ks ? b11 : b01;
                TRRD(tp[0].h[0], bh0, "0");   TRRD(tp[0].h[1], bh1, "0");
                TRRD(tp[1].h[0], bh0, "128"); TRRD(tp[1].h[1], bh1, "128");
                TRRD(tp[2].h[0], bh0, "256"); TRRD(tp[2].h[1], bh1, "256");
                TRRD(tp[3].h[0], bh0, "384"); TRRD(tp[3].h[1], bh1, "384");
                asm volatile("s_waitcnt lgkmcnt(0)" ::: "memory");
                __builtin_amdgcn_sched_barrier(0);

                union { unsigned w[4]; f16x8 v; } pau;
                pau.w[0] = T[ks][0]; pau.w[1] = T[ks][1];
                pau.w[2] = T[ks][2]; pau.w[3] = T[ks][3];

                __builtin_amdgcn_s_setprio(1);
#pragma unroll
                for (int nt = 0; nt < 4; ++nt)
                    acc[u][nt] = __builtin_amdgcn_mfma_f32_16x16x32_f16(pau.v, tp[nt].v8, acc[u][nt], 0, 0, 0);
                __builtin_amdgcn_s_setprio(0);
            }
        }

        if (t + 1 < NTILE) {
            STAGE_WRITE(c ^ 1);
            __syncthreads();
        }
    }

#pragma unroll
    for (int u = 0; u < 2; ++u)
#pragma unroll
        for (int r = 0; r < 4; ++r) {
            const float lr  = __shfl(l_run[u], 4 * g + r);
            const float inv = 1.0f / lr;
            const int row = qb0 + wv * 32 + u * 16 + 4 * g + r;
            float* op = Og + base + (size_t)row * DH;
#pragma unroll
            for (int nt = 0; nt < 4; ++nt)
                op[16 * nt + l15] = acc[u][nt][r] * inv;
        }
}

extern "C" void kernel_launch(void* const* d_in, const int* in_sizes, int n_in,
                              void* d_out, int out_size, void* d_ws, size_t ws_size,
                              hipStream_t stream) {
    const float* Q = (const float*)d_in[0];
    const float* K = (const float*)d_in[1];
    const float* V = (const float*)d_in[2];
    float* O = (float*)d_out;
    fa_fwd<<<dim3(512, 1, 1), dim3(512, 1, 1), 0, stream>>>(Q, K, V, O);
}

// Round 7
// 118.292 us; speedup vs baseline: 1.1713x; 1.1713x over previous
//
#include <hip/hip_runtime.h>

#define NSEQ 2048
#define DH 64
#define SCALE 0.125f
#define QBLK 256
#define KVBLK 64
#define NTILE (NSEQ / KVBLK)
#define KP 72   // Kt row pitch (144B): conflict-minimal b128 reads + writes

typedef _Float16 f16x8 __attribute__((ext_vector_type(8)));
typedef _Float16 f16x4 __attribute__((ext_vector_type(4)));
typedef __fp16 fp16x2 __attribute__((ext_vector_type(2)));
typedef float f32x4 __attribute__((ext_vector_type(4)));
typedef unsigned u32x2 __attribute__((ext_vector_type(2)));

union TrP { f16x4 h[2]; f16x8 v8; };

// tr-read: per-lane addr = subtile_base + l15*8; HW delivers column l15 of the
// 128B-aligned 4x16 f16 subtile. Subtile bases MUST be 128B-aligned.
#define TRRD(dst, bb, lit) \
    asm volatile("ds_read_b64_tr_b16 %0, %1 offset:" lit : "=v"(dst) : "v"(bb))

__global__ __launch_bounds__(512, 4)
void fa_fwd(const float* __restrict__ Qg, const float* __restrict__ Kg,
            const float* __restrict__ Vg, float* __restrict__ Og)
{
    __shared__ _Float16 Kt[2][KVBLK * KP];   // 18432 B, double-buffered
    __shared__ _Float16 Vt[2][KVBLK * DH];   // 16384 B, subtiled [kv/4][d/16][4][16]

    const int tid  = threadIdx.x;
    const int lane = tid & 63;
    const int wv   = tid >> 6;
    const int l15  = lane & 15;
    const int g    = lane >> 4;

    // XCD-aware swizzle: 512 blocks / 8 XCDs
    const int id  = blockIdx.x;
    const int w   = (id & 7) * 64 + (id >> 3);
    const int bh  = w >> 3;
    const int qb0 = (w & 7) * QBLK;
    const size_t base = (size_t)bh * NSEQ * DH;

    f16x8 qf[2][2];
#pragma unroll
    for (int u = 0; u < 2; ++u) {
        const float* qp = Qg + base + (size_t)(qb0 + wv * 32 + u * 16 + l15) * DH;
#pragma unroll
        for (int ks = 0; ks < 2; ++ks)
#pragma unroll
            for (int j = 0; j < 8; ++j)
                qf[u][ks][j] = (_Float16)(qp[32 * ks + 8 * g + j] * SCALE);
    }

    f32x4 acc[2][4];
#pragma unroll
    for (int u = 0; u < 2; ++u)
#pragma unroll
        for (int nt = 0; nt < 4; ++nt)
            acc[u][nt] = (f32x4){0.f, 0.f, 0.f, 0.f};
    float m_run[2] = {-INFINITY, -INFINITY};
    float l_run[2] = {0.f, 0.f};

    // staging map: each thread 2 float4 per K and V
    const int ea  = tid * 4;
    const int eb  = 2048 + tid * 4;
    const int kva = ea >> 6, d0a = ea & 63;
    const int kvb = eb >> 6, d0b = eb & 63;
    const float* Kbp = Kg + base;
    const float* Vbp = Vg + base;
    const int vta = ((kva >> 2) * 4 + (d0a >> 4)) * 64 + (kva & 3) * 16 + (d0a & 15);
    const int vtb = ((kvb >> 2) * 4 + (d0b >> 4)) * 64 + (kvb & 3) * 16 + (d0b & 15);

    float4 kra, krb, vra, vrb;
    kra = *(const float4*)(Kbp + kva * DH + d0a);
    krb = *(const float4*)(Kbp + kvb * DH + d0b);
    vra = *(const float4*)(Vbp + kva * DH + d0a);
    vrb = *(const float4*)(Vbp + kvb * DH + d0b);

#define STAGE_WRITE(bb) do { \
        f16x4 h; \
        h[0] = (_Float16)kra.x; h[1] = (_Float16)kra.y; h[2] = (_Float16)kra.z; h[3] = (_Float16)kra.w; \
        *(f16x4*)&Kt[bb][kva * KP + d0a] = h; \
        h[0] = (_Float16)krb.x; h[1] = (_Float16)krb.y; h[2] = (_Float16)krb.z; h[3] = (_Float16)krb.w; \
        *(f16x4*)&Kt[bb][kvb * KP + d0b] = h; \
        h[0] = (_Float16)vra.x; h[1] = (_Float16)vra.y; h[2] = (_Float16)vra.z; h[3] = (_Float16)vra.w; \
        *(f16x4*)&Vt[bb][vta] = h; \
        h[0] = (_Float16)vrb.x; h[1] = (_Float16)vrb.y; h[2] = (_Float16)vrb.z; h[3] = (_Float16)vrb.w; \
        *(f16x4*)&Vt[bb][vtb] = h; \
    } while (0)

    STAGE_WRITE(0);
    __syncthreads();

    const unsigned vtrb = (unsigned)(size_t)(&Vt[0][0]) + (unsigned)(g * 1024 + l15 * 8);

    for (int t = 0; t < NTILE; ++t) {
        const int c = t & 1;

        // T14: issue next tile's global loads before compute
        if (t + 1 < NTILE) {
            const float* kp = Kbp + (size_t)(t + 1) * KVBLK * DH;
            const float* vp = Vbp + (size_t)(t + 1) * KVBLK * DH;
            kra = *(const float4*)(kp + kva * DH + d0a);
            krb = *(const float4*)(kp + kvb * DH + d0b);
            vra = *(const float4*)(vp + kva * DH + d0a);
            vrb = *(const float4*)(vp + kvb * DH + d0b);
        }

        // tr-read bases: subtile (kv4 = 8ks+2g+h2, d16 = nt) at 128B-aligned offsets
        const unsigned vb  = vtrb + (unsigned)(c * 8192);
        const unsigned b00 = vb;            // ks=0, h2=0
        const unsigned b01 = vb + 512u;     // ks=0, h2=1
        const unsigned b10 = vb + 4096u;    // ks=1, h2=0
        const unsigned b11 = vb + 4608u;    // ks=1, h2=1

#pragma unroll
        for (int u = 0; u < 2; ++u) {
            // S^T = K·Q^T; K fragments loaded per-mt (transient regs)
            f32x4 s[4];
            __builtin_amdgcn_s_setprio(1);
#pragma unroll
            for (int mt = 0; mt < 4; ++mt) {
                const f16x8 k0 = *(const f16x8*)&Kt[c][(l15 + 16 * mt) * KP + 8 * g];
                const f16x8 k1 = *(const f16x8*)&Kt[c][(l15 + 16 * mt) * KP + 32 + 8 * g];
                s[mt] = __builtin_amdgcn_mfma_f32_16x16x32_f16(k0, qf[u][0],
                            (f32x4){0.f, 0.f, 0.f, 0.f}, 0, 0, 0);
                s[mt] = __builtin_amdgcn_mfma_f32_16x16x32_f16(k1, qf[u][1], s[mt], 0, 0, 0);
            }
            __builtin_amdgcn_s_setprio(0);

            // tile max via max3-friendly nesting
            float m0 = fmaxf(fmaxf(s[0][0], s[0][1]), s[0][2]);
            float m1 = fmaxf(fmaxf(s[0][3], s[1][0]), s[1][1]);
            float m2 = fmaxf(fmaxf(s[1][2], s[1][3]), s[2][0]);
            float m3 = fmaxf(fmaxf(s[2][1], s[2][2]), s[2][3]);
            float m4 = fmaxf(fmaxf(s[3][0], s[3][1]), s[3][2]);
            float tmax = fmaxf(fmaxf(m0, m1), fmaxf(fmaxf(m2, m3), fmaxf(m4, s[3][3])));
            tmax = fmaxf(tmax, __shfl_xor(tmax, 16));
            tmax = fmaxf(tmax, __shfl_xor(tmax, 32));

            // T13 defer-max
            if (!__all(tmax <= m_run[u] + 8.f)) {
                const float m_new = fmaxf(m_run[u], tmax);
                const float fac = __expf(m_run[u] - m_new);
                l_run[u] *= fac;
                m_run[u] = m_new;
#pragma unroll
                for (int r = 0; r < 4; ++r) {
                    const float fr = __shfl(fac, 4 * g + r);
#pragma unroll
                    for (int nt = 0; nt < 4; ++nt) acc[u][nt][r] *= fr;
                }
            }

            // P = exp(s - m) packed to f16 pairs: W[mt][h] = pair at kv 16mt+4g+2h
            unsigned W[4][2];
            float psum = 0.f;
#pragma unroll
            for (int mt = 0; mt < 4; ++mt) {
                float p0 = __expf(s[mt][0] - m_run[u]);
                float p1 = __expf(s[mt][1] - m_run[u]);
                float p2 = __expf(s[mt][2] - m_run[u]);
                float p3 = __expf(s[mt][3] - m_run[u]);
                psum += (p0 + p1) + (p2 + p3);
                union { fp16x2 f2; unsigned w; } u0, u1;
                u0.f2 = __builtin_amdgcn_cvt_pkrtz(p0, p1);
                u1.f2 = __builtin_amdgcn_cvt_pkrtz(p2, p3);
                W[mt][0] = u0.w;
                W[mt][1] = u1.w;
            }
            psum += __shfl_xor(psum, 16);
            psum += __shfl_xor(psum, 32);
            l_run[u] += psum;

#pragma unroll
            for (int ks = 0; ks < 2; ++ks) {
                // T12 routing, transient: a=W[2ks][h], b=W[2ks+1][h];
                // 32-swap then 16-swap -> Ta[h], Ta[2+h]
                unsigned Ta[4];
#pragma unroll
                for (int h = 0; h < 2; ++h) {
                    u32x2 r1 = __builtin_amdgcn_permlane32_swap(W[2 * ks][h], W[2 * ks + 1][h], false, false);
                    u32x2 r2 = __builtin_amdgcn_permlane16_swap(r1[0], r1[1], false, false);
                    Ta[h]     = r2[0];
                    Ta[2 + h] = r2[1];
                }

                TrP tp[4];
                const unsigned bh0 = ks ? b10 : b00;
                const unsigned bh1 = ks ? b11 : b01;
                TRRD(tp[0].h[0], bh0, "0");   TRRD(tp[0].h[1], bh1, "0");
                TRRD(tp[1].h[0], bh0, "128"); TRRD(tp[1].h[1], bh1, "128");
                TRRD(tp[2].h[0], bh0, "256"); TRRD(tp[2].h[1], bh1, "256");
                TRRD(tp[3].h[0], bh0, "384"); TRRD(tp[3].h[1], bh1, "384");
                asm volatile("s_waitcnt lgkmcnt(0)" ::: "memory");
                __builtin_amdgcn_sched_barrier(0);

                union { unsigned w[4]; f16x8 v; } pau;
                pau.w[0] = Ta[0]; pau.w[1] = Ta[1];
                pau.w[2] = Ta[2]; pau.w[3] = Ta[3];

                __builtin_amdgcn_s_setprio(1);
#pragma unroll
                for (int nt = 0; nt < 4; ++nt)
                    acc[u][nt] = __builtin_amdgcn_mfma_f32_16x16x32_f16(pau.v, tp[nt].v8, acc[u][nt], 0, 0, 0);
                __builtin_amdgcn_s_setprio(0);
            }
        }

        if (t + 1 < NTILE) {
            STAGE_WRITE(c ^ 1);
            __syncthreads();
        }
    }

#pragma unroll
    for (int u = 0; u < 2; ++u)
#pragma unroll
        for (int r = 0; r < 4; ++r) {
            const float lr  = __shfl(l_run[u], 4 * g + r);
            const float inv = 1.0f / lr;
            const int row = qb0 + wv * 32 + u * 16 + 4 * g + r;
            float* op = Og + base + (size_t)row * DH;
#pragma unroll
            for (int nt = 0; nt < 4; ++nt)
                op[16 * nt + l15] = acc[u][nt][r] * inv;
        }
}

extern "C" void kernel_launch(void* const* d_in, const int* in_sizes, int n_in,
                              void* d_out, int out_size, void* d_ws, size_t ws_size,
                              hipStream_t stream) {
    const float* Q = (const float*)d_in[0];
    const float* K = (const float*)d_in[1];
    const float* V = (const float*)d_in[2];
    float* O = (float*)d_out;
    fa_fwd<<<dim3(512, 1, 1), dim3(512, 1, 1), 0, stream>>>(Q, K, V, O);
}